// Round 6
// baseline (164.422 us; speedup 1.0000x reference)
//
#include <hip/hip_runtime.h>
#include <cstddef>

typedef float f32x4 __attribute__((ext_vector_type(4)));
typedef short s16x4 __attribute__((ext_vector_type(4)));
typedef short s16x8 __attribute__((ext_vector_type(8)));
typedef __bf16 bf16x8 __attribute__((ext_vector_type(8)));

#define NB 8
#define NS 1024
#define ND 768
#define NH 12
#define HD 64

template <int V> struct IC { static constexpr int value = V; };

__device__ __forceinline__ unsigned short f2bf(float f) {
  unsigned u = __builtin_bit_cast(unsigned, f);
  u += 0x7fffu + ((u >> 16) & 1u);
  return (unsigned short)(u >> 16);
}

__device__ __forceinline__ f32x4 mfma16(bf16x8 a, bf16x8 b, f32x4 c) {
  return __builtin_amdgcn_mfma_f32_16x16x32_bf16(a, b, c, 0, 0, 0);
}

__device__ __forceinline__ bf16x8 ld8(const unsigned short* p) {
  return *reinterpret_cast<const bf16x8*>(p);
}

__device__ __forceinline__ void gload16(unsigned short* lds_dst, const unsigned short* gsrc) {
  __builtin_amdgcn_global_load_lds(
      (const __attribute__((address_space(1))) unsigned int*)gsrc,
      (__attribute__((address_space(3))) unsigned int*)lds_dst, 16, 0, 0);
}

// phase boundary: raw barrier (no vmcnt drain), pinned against code motion
#define PB()                              \
  do {                                    \
    __builtin_amdgcn_sched_barrier(0);    \
    __builtin_amdgcn_s_barrier();         \
    __builtin_amdgcn_sched_barrier(0);    \
  } while (0)
// all LDS reads complete (rule 18: sched_barrier after inline-asm lgkmcnt)
#define LGKM0()                                          \
  do {                                                   \
    asm volatile("s_waitcnt lgkmcnt(0)" ::: "memory");   \
    __builtin_amdgcn_sched_barrier(0);                   \
  } while (0)
#define VMW(N) asm volatile("s_waitcnt vmcnt(" #N ")" ::: "memory")

// ---------------- pack kernels ----------------

__global__ __launch_bounds__(256) void cvt_f32_bf16(const float* __restrict__ in,
                                                    unsigned short* __restrict__ out) {
  int i = (blockIdx.x * 256 + threadIdx.x) * 4;
  float4 v = *reinterpret_cast<const float4*>(in + i);
  ushort4 o;
  o.x = f2bf(v.x); o.y = f2bf(v.y); o.z = f2bf(v.z); o.w = f2bf(v.w);
  *reinterpret_cast<ushort4*>(out + i) = o;
}

__global__ __launch_bounds__(256) void transpose_cvt(const float* __restrict__ in,
                                                     unsigned short* __restrict__ out,
                                                     int R, int C) {
  __shared__ float tile[32][33];
  int c0 = blockIdx.x * 32, r0 = blockIdx.y * 32;
  int tx = threadIdx.x & 31, ty = threadIdx.x >> 5;
#pragma unroll
  for (int i = 0; i < 32; i += 8)
    tile[ty + i][tx] = in[(size_t)(r0 + ty + i) * C + c0 + tx];
  __syncthreads();
#pragma unroll
  for (int i = 0; i < 32; i += 8)
    out[(size_t)(c0 + ty + i) * R + r0 + tx] = f2bf(tile[tx][ty + i]);
}

__global__ __launch_bounds__(256) void transpose_v(const unsigned short* __restrict__ vw,
                                                   unsigned short* __restrict__ vt) {
  __shared__ unsigned short tile[32][33];
  int bh = blockIdx.z;
  int d0 = blockIdx.x * 32, s0 = blockIdx.y * 32;
  const unsigned short* in = vw + (size_t)bh * NS * HD;
  unsigned short* out = vt + (size_t)bh * HD * NS;
  int tx = threadIdx.x & 31, ty = threadIdx.x >> 5;
#pragma unroll
  for (int i = 0; i < 32; i += 8)
    tile[ty + i][tx] = in[(size_t)(s0 + ty + i) * HD + d0 + tx];
  __syncthreads();
#pragma unroll
  for (int i = 0; i < 32; i += 8)
    out[(size_t)(d0 + ty + i) * NS + s0 + tx] = tile[tx][ty + i];
}

// ---------------- 8-phase GEMM mainloop (m201 template port) ----------------
// BM=256, BN=NF*128, BK=64, 8 waves (2M x 4N), per-wave out 128 x NF*32.
// Double-buffered K-tiles; 4 phases per K-tile; 1 half-tile staged per phase;
// counted vmcnt (6 for NF=2, 4 for NF=1) once per K-tile, vmcnt(0) only at tail.
// T2 swizzle (r5-verified, 0 conflicts): LDS (row, c16) holds global (row, c16^(row&7));
// stage applies inverse on the per-lane GLOBAL col, dest stays lane-linear.
// Stage schedule: p0 -> A1(t+1) [other buf], p1 -> A0(t+2), p2 -> B0(t+2), p3 -> B1(t+2).
// Race audit: each staged region's last LDS read completes at the previous
// phase's LGKM0 + barrier; vmcnt at (t,3) guarantees stages <= (t,0) landed,
// i.e. tile t+1 fully staged before its first read at (t+1,0).

template <int NF>
__device__ __forceinline__ void gemm_mainloop8(const unsigned short* __restrict__ A,
                                               const unsigned short* __restrict__ Bt,
                                               int m0, int n0, unsigned short* smem,
                                               f32x4 (&acc)[2][4][2 * NF]) {
  constexpr int K = 768;
  constexpr int nt = K / 64;       // 12 (even)
  constexpr int ASH = 256 * 64;    // shorts per A buffer
  constexpr int BSH = NF * 128 * 64;
  constexpr int BUFS = ASH + BSH;
  constexpr int WCW = 32 * NF;     // per-wave col width

  const int tid = threadIdx.x, lane = tid & 63, wid = tid >> 6;
  const int wr = wid >> 2, wn = wid & 3;
  const int ll = lane & 15, lh = lane >> 4;
  const int g8 = lane >> 3, c8 = lane & 7;
  const int swz = (c8 ^ g8) * 8;  // inverse-swizzled global source col (shorts)

  const unsigned short* aB = A + (size_t)(m0 + wid * 8 + g8) * K + swz;
  const unsigned short* bB;
  if constexpr (NF == 2)
    bB = Bt + (size_t)(n0 + (wid >> 2) * 64 + (wid & 3) * 8 + g8) * K + swz;
  else
    bB = Bt + (size_t)(n0 + (wid >> 1) * 32 + (wid & 1) * 8 + g8) * K + swz;

  unsigned short* aD = smem + wid * 512;  // wave-uniform lane-linear dest
  unsigned short* bD;
  if constexpr (NF == 2)
    bD = smem + ASH + (wid >> 2) * 4096 + (wid & 3) * 512;
  else
    bD = smem + ASH + (wid >> 1) * 2048 + (wid & 1) * 512;

  auto SA0 = [&](int buf, int t) {  // A rows {0-63, 128-191}
    unsigned short* d = aD + buf * BUFS;
    const unsigned short* s = aB + t * 64;
    gload16(d, s);
    gload16(d + 128 * 64, s + 128 * K);
  };
  auto SA1 = [&](int buf, int t) {  // A rows {64-127, 192-255}
    unsigned short* d = aD + buf * BUFS;
    const unsigned short* s = aB + t * 64;
    gload16(d + 64 * 64, s + 64 * K);
    gload16(d + 192 * 64, s + 192 * K);
  };
  auto SB0 = [&](int buf, int t) {  // B first col-halves
    unsigned short* d = bD + buf * BUFS;
    const unsigned short* s = bB + t * 64;
    gload16(d, s);
    if constexpr (NF == 2) gload16(d + 128 * 64, s + 128 * K);
  };
  auto SB1 = [&](int buf, int t) {  // B second col-halves
    unsigned short* d = bD + buf * BUFS;
    const unsigned short* s = bB + t * 64;
    if constexpr (NF == 2) {
      gload16(d + 32 * 64, s + 32 * K);
      gload16(d + 160 * 64, s + 160 * K);
    } else {
      gload16(d + 16 * 64, s + 16 * K);
    }
  };

  // swizzled ds_read column offsets (shorts) for k-halves 0/1
  const int r8 = ll & 7;
  const int sw0 = (lh ^ r8) * 8;
  const int sw1 = ((4 + lh) ^ r8) * 8;
  const int arow = (wr * 128 + ll) * 64;
  const int brow = (wn * WCW + ll) * 64;

  // prologue: fully stage K-tiles 0 (buf0) and 1 (buf1)
  SA0(0, 0); SA1(0, 0); SB0(0, 0); SB1(0, 0);
  SA0(1, 1); SA1(1, 1); SB0(1, 1); SB1(1, 1);
  if constexpr (NF == 2) VMW(8); else VMW(6);  // tile0 landed, tile1 in flight
  PB();

  auto ktile = [&](auto bufc, int t) {
    constexpr int BUF = decltype(bufc)::value;
    const unsigned short* Ab = smem + BUF * BUFS;
    const unsigned short* Bb = Ab + ASH;
    bf16x8 a[4][2], b0[NF][2], b1[NF][2];

    // ---- phase 0: read A0 + B0; stage A1(t+1); MFMA quadrant (0,0)
#pragma unroll
    for (int m = 0; m < 4; m++) {
      a[m][0] = ld8(Ab + arow + m * 1024 + sw0);
      a[m][1] = ld8(Ab + arow + m * 1024 + sw1);
    }
#pragma unroll
    for (int nn = 0; nn < NF; nn++) {
      b0[nn][0] = ld8(Bb + brow + nn * 1024 + sw0);
      b0[nn][1] = ld8(Bb + brow + nn * 1024 + sw1);
    }
    if (t >= 1 && t + 1 < nt) SA1(BUF ^ 1, t + 1);
    PB();
    LGKM0();
    __builtin_amdgcn_s_setprio(1);
#pragma unroll
    for (int m = 0; m < 4; m++)
#pragma unroll
      for (int nn = 0; nn < NF; nn++) {
        acc[0][m][nn] = mfma16(a[m][0], b0[nn][0], acc[0][m][nn]);
        acc[0][m][nn] = mfma16(a[m][1], b0[nn][1], acc[0][m][nn]);
      }
    __builtin_amdgcn_s_setprio(0);
    PB();

    // ---- phase 1: read B1; stage A0(t+2); MFMA quadrant (0,1)
#pragma unroll
    for (int nn = 0; nn < NF; nn++) {
      b1[nn][0] = ld8(Bb + brow + NF * 1024 + nn * 1024 + sw0);
      b1[nn][1] = ld8(Bb + brow + NF * 1024 + nn * 1024 + sw1);
    }
    if (t + 2 < nt) SA0(BUF, t + 2);
    PB();
    LGKM0();
    __builtin_amdgcn_s_setprio(1);
#pragma unroll
    for (int m = 0; m < 4; m++)
#pragma unroll
      for (int nn = 0; nn < NF; nn++) {
        acc[0][m][NF + nn] = mfma16(a[m][0], b1[nn][0], acc[0][m][NF + nn]);
        acc[0][m][NF + nn] = mfma16(a[m][1], b1[nn][1], acc[0][m][NF + nn]);
      }
    __builtin_amdgcn_s_setprio(0);
    PB();

    // ---- phase 2: read A1 (reuse a[]); stage B0(t+2); MFMA quadrant (1,0)
#pragma unroll
    for (int m = 0; m < 4; m++) {
      a[m][0] = ld8(Ab + arow + 4096 + m * 1024 + sw0);
      a[m][1] = ld8(Ab + arow + 4096 + m * 1024 + sw1);
    }
    if (t + 2 < nt) SB0(BUF, t + 2);
    PB();
    LGKM0();
    __builtin_amdgcn_s_setprio(1);
#pragma unroll
    for (int m = 0; m < 4; m++)
#pragma unroll
      for (int nn = 0; nn < NF; nn++) {
        acc[1][m][nn] = mfma16(a[m][0], b0[nn][0], acc[1][m][nn]);
        acc[1][m][nn] = mfma16(a[m][1], b0[nn][1], acc[1][m][nn]);
      }
    __builtin_amdgcn_s_setprio(0);
    PB();

    // ---- phase 3: stage B1(t+2); MFMA quadrant (1,1); counted vmcnt
    if (t + 2 < nt) SB1(BUF, t + 2);
    PB();
    __builtin_amdgcn_s_setprio(1);
#pragma unroll
    for (int m = 0; m < 4; m++)
#pragma unroll
      for (int nn = 0; nn < NF; nn++) {
        acc[1][m][NF + nn] = mfma16(a[m][0], b1[nn][0], acc[1][m][NF + nn]);
        acc[1][m][NF + nn] = mfma16(a[m][1], b1[nn][1], acc[1][m][NF + nn]);
      }
    __builtin_amdgcn_s_setprio(0);
    if (t + 2 < nt) {
      if constexpr (NF == 2) VMW(6); else VMW(4);
    } else {
      VMW(0);
    }
    PB();
  };

  for (int t = 0; t < nt; t += 2) {
    ktile(IC<0>{}, t);
    ktile(IC<1>{}, t + 1);
  }
}

// ---------------- QKV GEMM (NF=2: 256x256 tile) ----------------

__global__ __launch_bounds__(512, 2) void qkv_gemm(const unsigned short* __restrict__ xbf,
                                                   const unsigned short* __restrict__ WT,
                                                   const float* __restrict__ bias,
                                                   unsigned short* __restrict__ qw,
                                                   unsigned short* __restrict__ kw,
                                                   unsigned short* __restrict__ vw) {
  extern __shared__ __align__(16) unsigned short smem[];
  int m0 = blockIdx.y * 256, n0 = blockIdx.x * 256;
  f32x4 acc[2][4][4];
#pragma unroll
  for (int rh = 0; rh < 2; rh++)
#pragma unroll
    for (int m = 0; m < 4; m++)
#pragma unroll
      for (int n = 0; n < 4; n++) acc[rh][m][n] = (f32x4){0.f, 0.f, 0.f, 0.f};

  gemm_mainloop8<2>(xbf, WT, m0, n0, smem, acc);

  int tid = threadIdx.x, lane = tid & 63, wid = tid >> 6;
  int wr = wid >> 2, wn = wid & 3;
  int ll = lane & 15, lh = lane >> 4;
#pragma unroll
  for (int n = 0; n < 4; n++) {
    int col = n0 + wn * 64 + (n >> 1) * 32 + (n & 1) * 16 + ll;
    float bv = bias[col];
    int which = col / ND;
    int w2 = col - which * ND;
    int h = w2 >> 6, d = w2 & 63;
#pragma unroll
    for (int rh = 0; rh < 2; rh++) {
#pragma unroll
      for (int m = 0; m < 4; m++) {
#pragma unroll
        for (int r = 0; r < 4; r++) {
          int row = m0 + wr * 128 + rh * 64 + m * 16 + lh * 4 + r;
          int b = row >> 10, s = row & 1023;
          float v = acc[rh][m][n][r] + bv;
          size_t idx = (((size_t)b * NH + h) * NS + s) * HD + d;
          if (which == 0)
            qw[idx] = f2bf(v * 0.125f);
          else if (which == 1)
            kw[idx] = f2bf(v);
          else
            vw[idx] = f2bf(v);
        }
      }
    }
  }
}

// ---------------- proj GEMM (NF=1: 256x128 tile) ----------------

__global__ __launch_bounds__(512, 2) void proj_gemm(const unsigned short* __restrict__ abf,
                                                    const unsigned short* __restrict__ WT,
                                                    const float* __restrict__ bias,
                                                    float* __restrict__ out) {
  extern __shared__ __align__(16) unsigned short smem[];
  int m0 = blockIdx.y * 256, n0 = blockIdx.x * 128;
  f32x4 acc[2][4][2];
#pragma unroll
  for (int rh = 0; rh < 2; rh++)
#pragma unroll
    for (int m = 0; m < 4; m++)
#pragma unroll
      for (int n = 0; n < 2; n++) acc[rh][m][n] = (f32x4){0.f, 0.f, 0.f, 0.f};

  gemm_mainloop8<1>(abf, WT, m0, n0, smem, acc);

  int tid = threadIdx.x, lane = tid & 63, wid = tid >> 6;
  int wr = wid >> 2, wn = wid & 3;
  int ll = lane & 15, lh = lane >> 4;
#pragma unroll
  for (int n = 0; n < 2; n++) {
    int col = n0 + wn * 32 + n * 16 + ll;
    float bv = bias[col];
#pragma unroll
    for (int rh = 0; rh < 2; rh++) {
#pragma unroll
      for (int m = 0; m < 4; m++) {
#pragma unroll
        for (int r = 0; r < 4; r++) {
          int row = m0 + wr * 128 + rh * 64 + m * 16 + lh * 4 + r;
          out[(size_t)row * ND + col] = acc[rh][m][n][r] + bv;
        }
      }
    }
  }
}

// ---------------- flash attention (unchanged from r5) ----------------

#define LP 88

__global__ __launch_bounds__(512) void attn_kernel(const unsigned short* __restrict__ qw,
                                                   const unsigned short* __restrict__ kw,
                                                   const unsigned short* __restrict__ vt,
                                                   unsigned short* __restrict__ attn_out) {
  int qt = (int)gridDim.x - 1 - (int)blockIdx.x;
  int h = blockIdx.y, b = blockIdx.z;
  __shared__ __align__(16) unsigned short Ks[64 * LP];
  __shared__ __align__(16) unsigned short Vs[64 * LP];
  __shared__ __align__(16) unsigned short Ps[8][16 * LP];

  int tid = threadIdx.x, lane = tid & 63, wid = tid >> 6;
  int ll = lane & 15, lh = lane >> 4;
  int q0 = qt * 128;
  const size_t bh = ((size_t)b * NH + h) * NS * HD;

  int qrow = q0 + wid * 16 + ll;
  bf16x8 qf0 = ld8(&qw[bh + (size_t)qrow * HD + lh * 8]);
  bf16x8 qf1 = ld8(&qw[bh + (size_t)qrow * HD + 32 + lh * 8]);

  f32x4 o[4];
#pragma unroll
  for (int n = 0; n < 4; n++) o[n] = (f32x4){0.f, 0.f, 0.f, 0.f};
  float m_r = -1e30f, l_r = 0.f;

  int srow = tid >> 3, sc = (tid & 7) * 8;
  const unsigned short* ksrc = kw + bh + (size_t)srow * HD + sc;
  const unsigned short* vsrc = vt + bh + (size_t)srow * NS + sc;
  unsigned short* kdst = &Ks[srow * LP + sc];
  unsigned short* vdst = &Vs[srow * LP + sc];

  int qmaxw = q0 + wid * 16 + 15;
  int jend = q0 + 128;
  unsigned short* pw = &Ps[wid][ll * LP];

  for (int j0 = 0; j0 < jend; j0 += 64) {
    __syncthreads();
    *(s16x8*)kdst = *(const s16x8*)(ksrc + (size_t)j0 * HD);
    *(s16x8*)vdst = *(const s16x8*)(vsrc + j0);
    __syncthreads();

    if (j0 <= qmaxw) {
      f32x4 sa[4];
#pragma unroll
      for (int n = 0; n < 4; n++) {
        bf16x8 kf0 = ld8(&Ks[(n * 16 + ll) * LP + lh * 8]);
        bf16x8 kf1 = ld8(&Ks[(n * 16 + ll) * LP + 32 + lh * 8]);
        sa[n] = mfma16(kf0, qf0, (f32x4){0.f, 0.f, 0.f, 0.f});
        sa[n] = mfma16(kf1, qf1, sa[n]);
      }

      int qme = q0 + wid * 16 + ll;
      if (j0 + 63 > q0 + wid * 16) {
#pragma unroll
        for (int n = 0; n < 4; n++)
#pragma unroll
          for (int r = 0; r < 4; r++)
            if (j0 + n * 16 + lh * 4 + r > qme) sa[n][r] = -1e30f;
      }

      float t0 = fmaxf(fmaxf(sa[0][0], sa[0][1]), fmaxf(sa[0][2], sa[0][3]));
      float t1 = fmaxf(fmaxf(sa[1][0], sa[1][1]), fmaxf(sa[1][2], sa[1][3]));
      float t2 = fmaxf(fmaxf(sa[2][0], sa[2][1]), fmaxf(sa[2][2], sa[2][3]));
      float t3 = fmaxf(fmaxf(sa[3][0], sa[3][1]), fmaxf(sa[3][2], sa[3][3]));
      float tmax = fmaxf(fmaxf(t0, t1), fmaxf(t2, t3));
      tmax = fmaxf(tmax, __shfl_xor(tmax, 16));
      tmax = fmaxf(tmax, __shfl_xor(tmax, 32));
      float mnew = fmaxf(m_r, tmax);
      float alpha = __expf(m_r - mnew);
      m_r = mnew;

      float p[4][4];
      float ssum = 0.f;
#pragma unroll
      for (int n = 0; n < 4; n++)
#pragma unroll
        for (int r = 0; r < 4; r++) {
          p[n][r] = __expf(sa[n][r] - mnew);
          ssum += p[n][r];
        }
      ssum += __shfl_xor(ssum, 16);
      ssum += __shfl_xor(ssum, 32);
      l_r = alpha * l_r + ssum;

      float ab0 = __shfl(alpha, lh * 4 + 0);
      float ab1 = __shfl(alpha, lh * 4 + 1);
      float ab2 = __shfl(alpha, lh * 4 + 2);
      float ab3 = __shfl(alpha, lh * 4 + 3);
#pragma unroll
      for (int n2 = 0; n2 < 4; n2++) {
        o[n2][0] *= ab0; o[n2][1] *= ab1; o[n2][2] *= ab2; o[n2][3] *= ab3;
      }

#pragma unroll
      for (int n = 0; n < 4; n++) {
        s16x4 pk;
        pk[0] = (short)f2bf(p[n][0]);
        pk[1] = (short)f2bf(p[n][1]);
        pk[2] = (short)f2bf(p[n][2]);
        pk[3] = (short)f2bf(p[n][3]);
        *(s16x4*)&pw[n * 16 + lh * 4] = pk;
      }

#pragma unroll
      for (int c = 0; c < 2; c++) {
        bf16x8 pf = ld8(&pw[c * 32 + lh * 8]);
#pragma unroll
        for (int n2 = 0; n2 < 4; n2++) {
          bf16x8 vf = ld8(&Vs[(n2 * 16 + ll) * LP + c * 32 + lh * 8]);
          o[n2] = mfma16(pf, vf, o[n2]);
        }
      }
    }
  }

  float lrec = 1.0f / l_r;
  float lb0 = __shfl(lrec, lh * 4 + 0);
  float lb1 = __shfl(lrec, lh * 4 + 1);
  float lb2 = __shfl(lrec, lh * 4 + 2);
  float lb3 = __shfl(lrec, lh * 4 + 3);
#pragma unroll
  for (int n2 = 0; n2 < 4; n2++) {
    int d = n2 * 16 + ll;
    int qb = q0 + wid * 16 + lh * 4;
    attn_out[((size_t)b * NS + qb + 0) * ND + h * HD + d] = f2bf(o[n2][0] * lb0);
    attn_out[((size_t)b * NS + qb + 1) * ND + h * HD + d] = f2bf(o[n2][1] * lb1);
    attn_out[((size_t)b * NS + qb + 2) * ND + h * HD + d] = f2bf(o[n2][2] * lb2);
    attn_out[((size_t)b * NS + qb + 3) * ND + h * HD + d] = f2bf(o[n2][3] * lb3);
  }
}

// ---------------- launch ----------------

#define QKV_LDS 131072
#define PROJ_LDS 98304

extern "C" void kernel_launch(void* const* d_in, const int* in_sizes, int n_in,
                              void* d_out, int out_size, void* d_ws, size_t ws_size,
                              hipStream_t stream) {
  const float* x = (const float*)d_in[0];
  const float* Wqkv = (const float*)d_in[1];
  const float* bqkv = (const float*)d_in[2];
  const float* Wproj = (const float*)d_in[3];
  const float* bproj = (const float*)d_in[4];
  float* out = (float*)d_out;

  char* ws = (char*)d_ws;
  const size_t SZ_X = (size_t)NB * NS * ND * 2;
  const size_t SZ_WQKV = (size_t)ND * 3 * ND * 2;
  const size_t SZ_WPROJ = (size_t)ND * ND * 2;
  const size_t SZ_HEAD = (size_t)NB * NH * NS * HD;  // elements

  unsigned short* xbf = (unsigned short*)(ws);
  unsigned short* wqkvT = (unsigned short*)(ws + SZ_X);
  unsigned short* wprojT = (unsigned short*)(ws + SZ_X + SZ_WQKV);
  unsigned short* qw = (unsigned short*)(ws + SZ_X + SZ_WQKV + SZ_WPROJ);
  unsigned short* kw = qw + SZ_HEAD;
  unsigned short* vw = kw + SZ_HEAD;
  unsigned short* attn = vw + SZ_HEAD;
  unsigned short* vtb = xbf;  // reuse x's slot after qkv_gemm consumed it

  (void)in_sizes; (void)n_in; (void)out_size; (void)ws_size;

  hipFuncSetAttribute(reinterpret_cast<const void*>(qkv_gemm),
                      hipFuncAttributeMaxDynamicSharedMemorySize, QKV_LDS);
  hipFuncSetAttribute(reinterpret_cast<const void*>(proj_gemm),
                      hipFuncAttributeMaxDynamicSharedMemorySize, PROJ_LDS);

  cvt_f32_bf16<<<(NB * NS * ND) / 1024, 256, 0, stream>>>(x, xbf);
  transpose_cvt<<<dim3(3 * ND / 32, ND / 32), 256, 0, stream>>>(Wqkv, wqkvT, ND, 3 * ND);
  transpose_cvt<<<dim3(ND / 32, ND / 32), 256, 0, stream>>>(Wproj, wprojT, ND, ND);

  qkv_gemm<<<dim3(3 * ND / 256, NB * NS / 256), 512, QKV_LDS, stream>>>(
      xbf, wqkvT, bqkv, qw, kw, vw);

  transpose_v<<<dim3(HD / 32, NS / 32, NB * NH), 256, 0, stream>>>(vw, vtb);

  attn_kernel<<<dim3(NS / 128, NH, NB), 512, 0, stream>>>(qw, kw, vtb, attn);

  proj_gemm<<<dim3(ND / 128, NB * NS / 256), 512, PROJ_LDS, stream>>>(
      attn, wprojT, bproj, out);
}

// Round 7
// 157.434 us; speedup vs baseline: 1.0444x; 1.0444x over previous
//
#include <hip/hip_runtime.h>
#include <cstddef>

typedef float f32x4 __attribute__((ext_vector_type(4)));
typedef short s16x4 __attribute__((ext_vector_type(4)));
typedef short s16x8 __attribute__((ext_vector_type(8)));
typedef __bf16 bf16x8 __attribute__((ext_vector_type(8)));

#define NB 8
#define NS 1024
#define ND 768
#define NH 12
#define HD 64

__device__ __forceinline__ unsigned short f2bf(float f) {
  unsigned u = __builtin_bit_cast(unsigned, f);
  u += 0x7fffu + ((u >> 16) & 1u);
  return (unsigned short)(u >> 16);
}

__device__ __forceinline__ f32x4 mfma16(bf16x8 a, bf16x8 b, f32x4 c) {
  return __builtin_amdgcn_mfma_f32_16x16x32_bf16(a, b, c, 0, 0, 0);
}

__device__ __forceinline__ bf16x8 ld8(const unsigned short* p) {
  return *reinterpret_cast<const bf16x8*>(p);
}

__device__ __forceinline__ void gload16(unsigned short* lds_dst, const unsigned short* gsrc) {
  __builtin_amdgcn_global_load_lds(
      (const __attribute__((address_space(1))) unsigned int*)gsrc,
      (__attribute__((address_space(3))) unsigned int*)lds_dst, 16, 0, 0);
}

#define VMW(N) asm volatile("s_waitcnt vmcnt(" #N ")" ::: "memory")

// ---------------- pack kernels ----------------

__global__ __launch_bounds__(256) void cvt_f32_bf16(const float* __restrict__ in,
                                                    unsigned short* __restrict__ out) {
  int i = (blockIdx.x * 256 + threadIdx.x) * 4;
  float4 v = *reinterpret_cast<const float4*>(in + i);
  ushort4 o;
  o.x = f2bf(v.x); o.y = f2bf(v.y); o.z = f2bf(v.z); o.w = f2bf(v.w);
  *reinterpret_cast<ushort4*>(out + i) = o;
}

__global__ __launch_bounds__(256) void transpose_cvt(const float* __restrict__ in,
                                                     unsigned short* __restrict__ out,
                                                     int R, int C) {
  __shared__ float tile[32][33];
  int c0 = blockIdx.x * 32, r0 = blockIdx.y * 32;
  int tx = threadIdx.x & 31, ty = threadIdx.x >> 5;
#pragma unroll
  for (int i = 0; i < 32; i += 8)
    tile[ty + i][tx] = in[(size_t)(r0 + ty + i) * C + c0 + tx];
  __syncthreads();
#pragma unroll
  for (int i = 0; i < 32; i += 8)
    out[(size_t)(c0 + ty + i) * R + r0 + tx] = f2bf(tile[tx][ty + i]);
}

__global__ __launch_bounds__(256) void transpose_v(const unsigned short* __restrict__ vw,
                                                   unsigned short* __restrict__ vt) {
  __shared__ unsigned short tile[32][33];
  int bh = blockIdx.z;
  int d0 = blockIdx.x * 32, s0 = blockIdx.y * 32;
  const unsigned short* in = vw + (size_t)bh * NS * HD;
  unsigned short* out = vt + (size_t)bh * HD * NS;
  int tx = threadIdx.x & 31, ty = threadIdx.x >> 5;
#pragma unroll
  for (int i = 0; i < 32; i += 8)
    tile[ty + i][tx] = in[(size_t)(s0 + ty + i) * HD + d0 + tx];
  __syncthreads();
#pragma unroll
  for (int i = 0; i < 32; i += 8)
    out[(size_t)(d0 + ty + i) * NS + s0 + tx] = tile[tx][ty + i];
}

// ---------------- GEMM mainloop: 128x128 tile, BK=32, 4 waves, 3-slot counted vmcnt ----------------
// r5-verified discipline at smaller footprint: 48 KB LDS -> 3 resident blocks/CU (TLP).
// Swizzle (64B rows): physical (r, c16) holds logical (r, c16 ^ ((r>>1)&3)) -> <=2-way
// bank aliasing (free, m136). Stage applies the inverse on the GLOBAL source col
// (dest stays lane-linear per the global_load_lds rule); ds_read applies it on the col.
// Depth-2 prefetch: iter t stages tile t+2 into slot (t+2)%3, computes slot t%3,
// then VMW(4) (tile t+1's 4 loads landed, t+2's in flight) + raw barrier.
// Tail: VMW(0) once at t+2==nt; last iter falls through (own reads compiler-tracked).

#define SLOT 8192  // shorts per slot: A[128][32] + B[128][32]

__device__ __forceinline__ void gemm_mainloop(const unsigned short* __restrict__ A,
                                              const unsigned short* __restrict__ Bt,
                                              int K, int m0, int n0,
                                              unsigned short* smem,
                                              f32x4 (&acc)[4][4]) {
  int tid = threadIdx.x, lane = tid & 63, wid = tid >> 6;
  int wr = wid >> 1, wc = wid & 1;
  int ll = lane & 15, lh = lane >> 4;
  int swsrc = ((lane & 3) ^ ((lane >> 3) & 3)) * 8;  // inverse swizzle on global col

  const unsigned short* asrc = A + (size_t)(m0 + wid * 32 + (lane >> 2)) * K + swsrc;
  const unsigned short* bsrc = Bt + (size_t)(n0 + wid * 32 + (lane >> 2)) * K + swsrc;
  const int sw = (lh ^ ((ll >> 1) & 3)) * 8;  // swizzled ds_read col (shorts)
  const int nt = K / 32;

  auto stage = [&](int slot, int t) {
    unsigned short* ad = smem + slot * SLOT + wid * 1024;       // wave-uniform, lane-linear
    unsigned short* bd = smem + slot * SLOT + 4096 + wid * 1024;
    const unsigned short* as = asrc + t * 32;
    const unsigned short* bs = bsrc + t * 32;
    gload16(ad, as);
    gload16(ad + 512, as + (size_t)16 * K);
    gload16(bd, bs);
    gload16(bd + 512, bs + (size_t)16 * K);
  };

  stage(0, 0);
  stage(1, 1);
  VMW(4);  // tile 0 landed; tile 1 in flight
  __builtin_amdgcn_s_barrier();
  asm volatile("" ::: "memory");

  int slot = 0;
  for (int t = 0; t < nt; ++t) {
    if (t + 2 < nt) {
      int s2 = slot + 2; if (s2 >= 3) s2 -= 3;
      stage(s2, t + 2);
    }
    const unsigned short* Ab = smem + slot * SLOT;
    const unsigned short* Bb = Ab + 4096;

    __builtin_amdgcn_s_setprio(1);
    bf16x8 af[4], bg[4];
#pragma unroll
    for (int m = 0; m < 4; m++) af[m] = ld8(Ab + (wr * 64 + m * 16 + ll) * 32 + sw);
#pragma unroll
    for (int n = 0; n < 4; n++) bg[n] = ld8(Bb + (wc * 64 + n * 16 + ll) * 32 + sw);
#pragma unroll
    for (int m = 0; m < 4; m++)
#pragma unroll
      for (int n = 0; n < 4; n++) acc[m][n] = mfma16(af[m], bg[n], acc[m][n]);
    __builtin_amdgcn_s_setprio(0);

    if (t + 2 < nt) {
      VMW(4);  // tile t+1 landed; t+2 stays in flight
      __builtin_amdgcn_s_barrier();
      asm volatile("" ::: "memory");
    } else if (t + 2 == nt) {
      VMW(0);  // final in-flight tile: drain once
      __builtin_amdgcn_s_barrier();
      asm volatile("" ::: "memory");
    }
    slot++; if (slot == 3) slot = 0;
  }
}

// ---------------- QKV GEMM ----------------

__global__ __launch_bounds__(256, 3) void qkv_gemm(const unsigned short* __restrict__ xbf,
                                                   const unsigned short* __restrict__ WT,
                                                   const float* __restrict__ bias,
                                                   unsigned short* __restrict__ qw,
                                                   unsigned short* __restrict__ kw,
                                                   unsigned short* __restrict__ vw) {
  __shared__ __align__(16) unsigned short smem[3 * SLOT];
  int m0 = blockIdx.y * 128, n0 = blockIdx.x * 128;
  f32x4 acc[4][4];
#pragma unroll
  for (int m = 0; m < 4; m++)
#pragma unroll
    for (int n = 0; n < 4; n++) acc[m][n] = (f32x4){0.f, 0.f, 0.f, 0.f};

  gemm_mainloop(xbf, WT, ND, m0, n0, smem, acc);

  int tid = threadIdx.x, lane = tid & 63, wid = tid >> 6;
  int wr = wid >> 1, wc = wid & 1;
  int ll = lane & 15, lh = lane >> 4;
#pragma unroll
  for (int nf = 0; nf < 4; nf++) {
    int col = n0 + wc * 64 + nf * 16 + ll;
    float bv = bias[col];
    int which = col / ND;
    int w2 = col - which * ND;
    int h = w2 >> 6, d = w2 & 63;
#pragma unroll
    for (int mf = 0; mf < 4; mf++) {
#pragma unroll
      for (int r = 0; r < 4; r++) {
        int m = m0 + wr * 64 + mf * 16 + lh * 4 + r;
        int b = m >> 10, s = m & 1023;
        float v = acc[mf][nf][r] + bv;
        size_t idx = (((size_t)b * NH + h) * NS + s) * HD + d;
        if (which == 0)
          qw[idx] = f2bf(v * 0.125f);
        else if (which == 1)
          kw[idx] = f2bf(v);
        else
          vw[idx] = f2bf(v);
      }
    }
  }
}

// ---------------- proj GEMM ----------------

__global__ __launch_bounds__(256, 3) void proj_gemm(const unsigned short* __restrict__ abf,
                                                    const unsigned short* __restrict__ WT,
                                                    const float* __restrict__ bias,
                                                    float* __restrict__ out) {
  __shared__ __align__(16) unsigned short smem[3 * SLOT];
  int m0 = blockIdx.y * 128, n0 = blockIdx.x * 128;
  f32x4 acc[4][4];
#pragma unroll
  for (int m = 0; m < 4; m++)
#pragma unroll
    for (int n = 0; n < 4; n++) acc[m][n] = (f32x4){0.f, 0.f, 0.f, 0.f};

  gemm_mainloop(abf, WT, ND, m0, n0, smem, acc);

  int tid = threadIdx.x, lane = tid & 63, wid = tid >> 6;
  int wr = wid >> 1, wc = wid & 1;
  int ll = lane & 15, lh = lane >> 4;
#pragma unroll
  for (int nf = 0; nf < 4; nf++) {
    int col = n0 + wc * 64 + nf * 16 + ll;
    float bv = bias[col];
#pragma unroll
    for (int mf = 0; mf < 4; mf++) {
#pragma unroll
      for (int r = 0; r < 4; r++) {
        int m = m0 + wr * 64 + mf * 16 + lh * 4 + r;
        out[(size_t)m * ND + col] = acc[mf][nf][r] + bv;
      }
    }
  }
}

// ---------------- flash attention (unchanged from r5) ----------------

#define LP 88

__global__ __launch_bounds__(512) void attn_kernel(const unsigned short* __restrict__ qw,
                                                   const unsigned short* __restrict__ kw,
                                                   const unsigned short* __restrict__ vt,
                                                   unsigned short* __restrict__ attn_out) {
  int qt = (int)gridDim.x - 1 - (int)blockIdx.x;
  int h = blockIdx.y, b = blockIdx.z;
  __shared__ __align__(16) unsigned short Ks[64 * LP];
  __shared__ __align__(16) unsigned short Vs[64 * LP];
  __shared__ __align__(16) unsigned short Ps[8][16 * LP];

  int tid = threadIdx.x, lane = tid & 63, wid = tid >> 6;
  int ll = lane & 15, lh = lane >> 4;
  int q0 = qt * 128;
  const size_t bh = ((size_t)b * NH + h) * NS * HD;

  int qrow = q0 + wid * 16 + ll;
  bf16x8 qf0 = ld8(&qw[bh + (size_t)qrow * HD + lh * 8]);
  bf16x8 qf1 = ld8(&qw[bh + (size_t)qrow * HD + 32 + lh * 8]);

  f32x4 o[4];
#pragma unroll
  for (int n = 0; n < 4; n++) o[n] = (f32x4){0.f, 0.f, 0.f, 0.f};
  float m_r = -1e30f, l_r = 0.f;

  int srow = tid >> 3, sc = (tid & 7) * 8;
  const unsigned short* ksrc = kw + bh + (size_t)srow * HD + sc;
  const unsigned short* vsrc = vt + bh + (size_t)srow * NS + sc;
  unsigned short* kdst = &Ks[srow * LP + sc];
  unsigned short* vdst = &Vs[srow * LP + sc];

  int qmaxw = q0 + wid * 16 + 15;
  int jend = q0 + 128;
  unsigned short* pw = &Ps[wid][ll * LP];

  for (int j0 = 0; j0 < jend; j0 += 64) {
    __syncthreads();
    *(s16x8*)kdst = *(const s16x8*)(ksrc + (size_t)j0 * HD);
    *(s16x8*)vdst = *(const s16x8*)(vsrc + j0);
    __syncthreads();

    if (j0 <= qmaxw) {
      f32x4 sa[4];
#pragma unroll
      for (int n = 0; n < 4; n++) {
        bf16x8 kf0 = ld8(&Ks[(n * 16 + ll) * LP + lh * 8]);
        bf16x8 kf1 = ld8(&Ks[(n * 16 + ll) * LP + 32 + lh * 8]);
        sa[n] = mfma16(kf0, qf0, (f32x4){0.f, 0.f, 0.f, 0.f});
        sa[n] = mfma16(kf1, qf1, sa[n]);
      }

      int qme = q0 + wid * 16 + ll;
      if (j0 + 63 > q0 + wid * 16) {
#pragma unroll
        for (int n = 0; n < 4; n++)
#pragma unroll
          for (int r = 0; r < 4; r++)
            if (j0 + n * 16 + lh * 4 + r > qme) sa[n][r] = -1e30f;
      }

      float t0 = fmaxf(fmaxf(sa[0][0], sa[0][1]), fmaxf(sa[0][2], sa[0][3]));
      float t1 = fmaxf(fmaxf(sa[1][0], sa[1][1]), fmaxf(sa[1][2], sa[1][3]));
      float t2 = fmaxf(fmaxf(sa[2][0], sa[2][1]), fmaxf(sa[2][2], sa[2][3]));
      float t3 = fmaxf(fmaxf(sa[3][0], sa[3][1]), fmaxf(sa[3][2], sa[3][3]));
      float tmax = fmaxf(fmaxf(t0, t1), fmaxf(t2, t3));
      tmax = fmaxf(tmax, __shfl_xor(tmax, 16));
      tmax = fmaxf(tmax, __shfl_xor(tmax, 32));
      float mnew = fmaxf(m_r, tmax);
      float alpha = __expf(m_r - mnew);
      m_r = mnew;

      float p[4][4];
      float ssum = 0.f;
#pragma unroll
      for (int n = 0; n < 4; n++)
#pragma unroll
        for (int r = 0; r < 4; r++) {
          p[n][r] = __expf(sa[n][r] - mnew);
          ssum += p[n][r];
        }
      ssum += __shfl_xor(ssum, 16);
      ssum += __shfl_xor(ssum, 32);
      l_r = alpha * l_r + ssum;

      float ab0 = __shfl(alpha, lh * 4 + 0);
      float ab1 = __shfl(alpha, lh * 4 + 1);
      float ab2 = __shfl(alpha, lh * 4 + 2);
      float ab3 = __shfl(alpha, lh * 4 + 3);
#pragma unroll
      for (int n2 = 0; n2 < 4; n2++) {
        o[n2][0] *= ab0; o[n2][1] *= ab1; o[n2][2] *= ab2; o[n2][3] *= ab3;
      }

#pragma unroll
      for (int n = 0; n < 4; n++) {
        s16x4 pk;
        pk[0] = (short)f2bf(p[n][0]);
        pk[1] = (short)f2bf(p[n][1]);
        pk[2] = (short)f2bf(p[n][2]);
        pk[3] = (short)f2bf(p[n][3]);
        *(s16x4*)&pw[n * 16 + lh * 4] = pk;
      }

#pragma unroll
      for (int c = 0; c < 2; c++) {
        bf16x8 pf = ld8(&pw[c * 32 + lh * 8]);
#pragma unroll
        for (int n2 = 0; n2 < 4; n2++) {
          bf16x8 vf = ld8(&Vs[(n2 * 16 + ll) * LP + c * 32 + lh * 8]);
          o[n2] = mfma16(pf, vf, o[n2]);
        }
      }
    }
  }

  float lrec = 1.0f / l_r;
  float lb0 = __shfl(lrec, lh * 4 + 0);
  float lb1 = __shfl(lrec, lh * 4 + 1);
  float lb2 = __shfl(lrec, lh * 4 + 2);
  float lb3 = __shfl(lrec, lh * 4 + 3);
#pragma unroll
  for (int n2 = 0; n2 < 4; n2++) {
    int d = n2 * 16 + ll;
    int qb = q0 + wid * 16 + lh * 4;
    attn_out[((size_t)b * NS + qb + 0) * ND + h * HD + d] = f2bf(o[n2][0] * lb0);
    attn_out[((size_t)b * NS + qb + 1) * ND + h * HD + d] = f2bf(o[n2][1] * lb1);
    attn_out[((size_t)b * NS + qb + 2) * ND + h * HD + d] = f2bf(o[n2][2] * lb2);
    attn_out[((size_t)b * NS + qb + 3) * ND + h * HD + d] = f2bf(o[n2][3] * lb3);
  }
}

// ---------------- launch ----------------

extern "C" void kernel_launch(void* const* d_in, const int* in_sizes, int n_in,
                              void* d_out, int out_size, void* d_ws, size_t ws_size,
                              hipStream_t stream) {
  const float* x = (const float*)d_in[0];
  const float* Wqkv = (const float*)d_in[1];
  const float* bqkv = (const float*)d_in[2];
  const float* Wproj = (const float*)d_in[3];
  const float* bproj = (const float*)d_in[4];
  float* out = (float*)d_out;

  char* ws = (char*)d_ws;
  const size_t SZ_X = (size_t)NB * NS * ND * 2;
  const size_t SZ_WQKV = (size_t)ND * 3 * ND * 2;
  const size_t SZ_WPROJ = (size_t)ND * ND * 2;
  const size_t SZ_HEAD = (size_t)NB * NH * NS * HD;  // elements

  unsigned short* xbf = (unsigned short*)(ws);
  unsigned short* wqkvT = (unsigned short*)(ws + SZ_X);
  unsigned short* wprojT = (unsigned short*)(ws + SZ_X + SZ_WQKV);
  unsigned short* qw = (unsigned short*)(ws + SZ_X + SZ_WQKV + SZ_WPROJ);
  unsigned short* kw = qw + SZ_HEAD;
  unsigned short* vw = kw + SZ_HEAD;
  unsigned short* attn = vw + SZ_HEAD;
  unsigned short* vtb = xbf;  // reuse x's slot after qkv_gemm consumed it

  (void)in_sizes; (void)n_in; (void)out_size; (void)ws_size;

  cvt_f32_bf16<<<(NB * NS * ND) / 1024, 256, 0, stream>>>(x, xbf);
  transpose_cvt<<<dim3(3 * ND / 32, ND / 32), 256, 0, stream>>>(Wqkv, wqkvT, ND, 3 * ND);
  transpose_cvt<<<dim3(ND / 32, ND / 32), 256, 0, stream>>>(Wproj, wprojT, ND, ND);

  qkv_gemm<<<dim3(3 * ND / 128, NB * NS / 128), 256, 0, stream>>>(xbf, wqkvT, bqkv, qw, kw, vw);

  transpose_v<<<dim3(HD / 32, NS / 32, NB * NH), 256, 0, stream>>>(vw, vtb);

  attn_kernel<<<dim3(NS / 128, NH, NB), 512, 0, stream>>>(qw, kw, vtb, attn);

  proj_gemm<<<dim3(ND / 128, NB * NS / 128), 256, 0, stream>>>(attn, wprojT, bproj, out);
}